// Round 1
// baseline (746.542 us; speedup 1.0000x reference)
//
#include <hip/hip_runtime.h>

#define MULW 256
#define INV_SQRT3 0.5773502691896258f

typedef __bf16 bf16x8 __attribute__((ext_vector_type(8)));
typedef float f32x4 __attribute__((ext_vector_type(4)));

// Pack weights (fp32, [u][w] with middle dim 1) into bf16 MFMA-B-fragment order.
// dst matrix order: 0=w000(x1), 1=w110(xinv3), 2=w011(xinv3), 3=w101(xinv3)
// fragment layout for 16x16x32: B[k][w], lane l holds k = t*32 + (l>>4)*8 + e,
// w = j*16 + (l&15); flat index = (((t*16 + j)*64 + l)*8 + e)
__global__ void pack_weights(const float* __restrict__ w000,
                             const float* __restrict__ w011,
                             const float* __restrict__ w101,
                             const float* __restrict__ w110,
                             __bf16* __restrict__ dst) {
  int tid = blockIdx.x * blockDim.x + threadIdx.x;  // 4*65536 threads
  int mat = tid >> 16;
  int p = tid & 65535;
  int e = p & 7;
  int l = (p >> 3) & 63;
  int j = (p >> 9) & 15;
  int t = p >> 13;
  int k = t * 32 + ((l >> 4) << 3) + e;
  int w = j * 16 + (l & 15);
  const float* src;
  float scale;
  if (mat == 0) { src = w000; scale = 1.0f; }
  else if (mat == 1) { src = w110; scale = INV_SQRT3; }
  else if (mat == 2) { src = w011; scale = INV_SQRT3; }
  else { src = w101; scale = INV_SQRT3; }
  dst[tid] = (__bf16)(src[k * 256 + w] * scale);
}

// Main fused kernel: 16 rows per block, all 256 w-columns.
// Streams: 0: a1=s1*s2  1: b1=v1.v2  2: s1  3: v1_0  4: v1_1  5: v1_2
// acc: 0: out0 (streams0@W0 + 1@W1)  1: c (2@W2)  2..4: d_i (3,4,5 @ W3)
__global__ __launch_bounds__(256, 3)
void fctp_kernel(const float* __restrict__ x1, const float* __restrict__ x2,
                 const __bf16* __restrict__ wb, float* __restrict__ out) {
  __shared__ __align__(16) __bf16 As[6][16][264];
  __shared__ float4 sc[16];

  const int tid = threadIdx.x;
  const int n0 = blockIdx.x * 16;

  if (tid < 16) {
    sc[tid] = *(const float4*)(x2 + (size_t)(n0 + tid) * 4);
  }
  __syncthreads();

  // ---- staging: compute 6 bf16 A-streams into LDS ----
  {
    const int r = tid >> 4;   // row in tile
    const int c = tid & 15;   // 16-u chunk
    const float* xrow = x1 + (size_t)(n0 + r) * 1024;
    const float4 scr = sc[r];  // x: s2, y/z/w: v2

    float s1f[16];
    float v1f[48];
#pragma unroll
    for (int j2 = 0; j2 < 4; ++j2)
      *(float4*)&s1f[j2 * 4] = *(const float4*)(xrow + c * 16 + j2 * 4);
#pragma unroll
    for (int j2 = 0; j2 < 12; ++j2)
      *(float4*)&v1f[j2 * 4] = *(const float4*)(xrow + 256 + c * 48 + j2 * 4);

    __bf16 o[6][16] __attribute__((aligned(16)));
#pragma unroll
    for (int j = 0; j < 16; ++j) {
      float s1 = s1f[j];
      float v10 = v1f[3 * j], v11 = v1f[3 * j + 1], v12 = v1f[3 * j + 2];
      o[0][j] = (__bf16)(s1 * scr.x);
      o[1][j] = (__bf16)(v10 * scr.y + v11 * scr.z + v12 * scr.w);
      o[2][j] = (__bf16)s1;
      o[3][j] = (__bf16)v10;
      o[4][j] = (__bf16)v11;
      o[5][j] = (__bf16)v12;
    }
#pragma unroll
    for (int s = 0; s < 6; ++s) {
      *(bf16x8*)&As[s][r][c * 16] = *(const bf16x8*)&o[s][0];
      *(bf16x8*)&As[s][r][c * 16 + 8] = *(const bf16x8*)&o[s][8];
    }
  }
  __syncthreads();

  // ---- MFMA phase ----
  const int lane = tid & 63;
  const int wv = tid >> 6;        // wave id 0..3
  const int m = lane & 15;        // A row / C col
  const int q = lane >> 4;        // quad
  const int jbase = wv * 4;       // first of 4 n-tiles for this wave

  f32x4 acc[5][4];
#pragma unroll
  for (int s = 0; s < 5; ++s)
#pragma unroll
    for (int jn = 0; jn < 4; ++jn)
      acc[s][jn] = (f32x4){0.f, 0.f, 0.f, 0.f};

  const bf16x8* WB = (const bf16x8*)wb;  // 4 matrices x 8192 frag-elems

#pragma unroll 2
  for (int t = 0; t < 8; ++t) {
    bf16x8 a[6];
#pragma unroll
    for (int s = 0; s < 6; ++s)
      a[s] = *(const bf16x8*)&As[s][m][t * 32 + q * 8];
#pragma unroll
    for (int jn = 0; jn < 4; ++jn) {
      int idx = (t * 16 + (jbase + jn)) * 64 + lane;
      bf16x8 b0 = WB[idx];
      bf16x8 b1 = WB[8192 + idx];
      bf16x8 b2 = WB[16384 + idx];
      bf16x8 b3 = WB[24576 + idx];
      acc[0][jn] = __builtin_amdgcn_mfma_f32_16x16x32_bf16(a[0], b0, acc[0][jn], 0, 0, 0);
      acc[0][jn] = __builtin_amdgcn_mfma_f32_16x16x32_bf16(a[1], b1, acc[0][jn], 0, 0, 0);
      acc[1][jn] = __builtin_amdgcn_mfma_f32_16x16x32_bf16(a[2], b2, acc[1][jn], 0, 0, 0);
      acc[2][jn] = __builtin_amdgcn_mfma_f32_16x16x32_bf16(a[3], b3, acc[2][jn], 0, 0, 0);
      acc[3][jn] = __builtin_amdgcn_mfma_f32_16x16x32_bf16(a[4], b3, acc[3][jn], 0, 0, 0);
      acc[4][jn] = __builtin_amdgcn_mfma_f32_16x16x32_bf16(a[5], b3, acc[4][jn], 0, 0, 0);
    }
  }

  // ---- epilogue ----
  const int rbase = q * 4;
#pragma unroll
  for (int jn = 0; jn < 4; ++jn) {
    const int w = (jbase + jn) * 16 + m;
#pragma unroll
    for (int r4 = 0; r4 < 4; ++r4) {
      const int row = rbase + r4;
      const size_t nb = (size_t)(n0 + row) * 1024;
      const float4 s = sc[row];  // x: s2, y/z/w: v2
      out[nb + w] = acc[0][jn][r4];
      const float cc = acc[1][jn][r4];
      const float d0 = acc[2][jn][r4];
      const float d1 = acc[3][jn][r4];
      const float d2 = acc[4][jn][r4];
      out[nb + 256 + 3 * w + 0] = cc * s.y + d0 * s.x;
      out[nb + 256 + 3 * w + 1] = cc * s.z + d1 * s.x;
      out[nb + 256 + 3 * w + 2] = cc * s.w + d2 * s.x;
    }
  }
}

extern "C" void kernel_launch(void* const* d_in, const int* in_sizes, int n_in,
                              void* d_out, int out_size, void* d_ws, size_t ws_size,
                              hipStream_t stream) {
  const float* x1 = (const float*)d_in[0];
  const float* x2 = (const float*)d_in[1];
  const float* w000 = (const float*)d_in[2];
  const float* w011 = (const float*)d_in[3];
  const float* w101 = (const float*)d_in[4];
  const float* w110 = (const float*)d_in[5];
  __bf16* wb = (__bf16*)d_ws;  // 4 * 65536 bf16 = 512 KB

  const int n = in_sizes[0] / 1024;  // 100000

  pack_weights<<<1024, 256, 0, stream>>>(w000, w011, w101, w110, wb);
  fctp_kernel<<<n / 16, 256, 0, stream>>>(x1, x2, (const __bf16*)wb,
                                          (float*)d_out);
}